// Round 8
// baseline (291.916 us; speedup 1.0000x reference)
//
#include <hip/hip_runtime.h>
#include <hip/hip_bf16.h>
#include <math.h>

// Problem dims (fixed by reference)
#define BB 4
#define TT 1024
#define DD 1024
#define HPS 4          // heads per scale
#define C0 21
#define C1 41
#define N0 (HPS * C0)  // 84
#define N1 (HPS * C1)  // 164
#define NL 256         // padded combined logits width (84 + 164 = 248 -> 256)
#define BT (BB * TT)   // 4096
#define TB 64          // t-tile for window kernel
#define HALO 20
#define HB (TB + 2 * HALO)  // 104 rows staged
#define KSPLIT 2       // split-K for logits GEMM
#define LDP 72         // padded LDS row stride (64 + 8 ushorts) -> conflict-free

typedef unsigned int uint;
typedef __bf16 bf16x8 __attribute__((ext_vector_type(8)));
typedef float f32x4 __attribute__((ext_vector_type(4)));

__device__ __forceinline__ ushort f2bf(float f) {
    union { float f; uint u; } v; v.f = f;
    uint u = v.u;
    uint r = (u + 0x7FFFu + ((u >> 16) & 1u)) >> 16;
    return (ushort)r;
}
__device__ __forceinline__ float bf2f(ushort s) {
    union { uint u; float f; } v; v.u = ((uint)s) << 16;
    return v.f;
}

// ---------------- fused conversion kernel ----------------
#define RQ  4096
#define R1  (RQ + 2048)
#define R2  (R1 + 1024)
#define R3  (R2 + 96)
#define R4  (R3 + 192)

__device__ __forceinline__ void transpose_tile(
    const float* __restrict__ in, ushort* __restrict__ out,
    int K, int Nin, int n_base, int Npad, int nx, int ky, int tid)
{
    __shared__ float tile[32][33];
    const int tx = tid & 31;
    const int ty = tid >> 5;   // 0..7
    const int n0 = nx * 32;
    const int k0 = ky * 32;
    #pragma unroll
    for (int i = 0; i < 4; i++) {
        int k = k0 + ty + i * 8;
        int n = n0 + tx;
        float v = (k < K && n < Nin) ? in[(size_t)k * Nin + n] : 0.0f;
        tile[ty + i * 8][tx] = v;
    }
    __syncthreads();
    #pragma unroll
    for (int i = 0; i < 4; i++) {
        int n = n0 + ty + i * 8;
        int k = k0 + tx;
        if (n < Npad && k < K)
            out[(size_t)(n_base + n) * K + k] = f2bf(tile[tx][ty + i * 8]);
    }
}

__global__ __launch_bounds__(256) void convert_all(
    const float* __restrict__ query, ushort* __restrict__ query_bf,
    const float* __restrict__ W_qv,  ushort* __restrict__ WqvT,
    const float* __restrict__ W_out, ushort* __restrict__ WoutT,
    const float* __restrict__ W2_0, const float* __restrict__ W2_1,
    ushort* __restrict__ W2T)
{
    const int blk = blockIdx.x;
    const int tid = threadIdx.x;
    if (blk < RQ) {
        int i = blk * 1024 + tid * 4;
        float4 v = *(const float4*)(query + i);
        ushort4 o;
        o.x = f2bf(v.x); o.y = f2bf(v.y); o.z = f2bf(v.z); o.w = f2bf(v.w);
        *(ushort4*)(query_bf + i) = o;
    } else if (blk < R1) {
        int idx = blk - RQ;                // 64 x 32
        transpose_tile(W_qv, WqvT, DD, 2 * DD, 0, 2 * DD, idx & 63, idx >> 6, tid);
    } else if (blk < R2) {
        int idx = blk - R1;                // 32 x 32
        transpose_tile(W_out, WoutT, DD, DD, 0, DD, idx & 31, idx >> 5, tid);
    } else if (blk < R3) {
        int idx = blk - R2;                // 3 x 32
        transpose_tile(W2_0, W2T, DD, N0, 0, N0, idx % 3, idx / 3, tid);
    } else {
        int idx = blk - R3;                // 6 x 32
        transpose_tile(W2_1, W2T, DD, N1, N0, NL - N0, idx % 6, idx / 6, tid);
    }
}

// ---- bf16 MFMA GEMM, 128x128 tile, BK=64, VGPR-staged + ds_write pipeline ----
// A: [M][K] bf16 row-major. Bt: [N][K] bf16 row-major.
// NO global_load_lds (those serialize at memory latency per instruction).
// Staging: 8 x global_load_dwordx4 -> VGPRs (pipelined, single latency),
// ds_write_b128 into padded LDS [128][LDP]; fragment ds_read_b128 conflict-free.
// Pipeline: write regs(it) -> barrier -> {prefetch regs(it+1) || compute(it)} -> barrier.
// K, klen multiples of 64.
// mode 0: Cf[row*ldc+col] = acc
// mode 2: col<DD -> Cb = bf16(relu(acc)); else Cv = bf16(acc)
// mode 3: Cf[(bz*BT + row)*ldc + col] = acc   (split-K partial)
__global__ __launch_bounds__(256, 2) void gemm_pipe(
    const ushort* __restrict__ A, const ushort* __restrict__ Bt,
    int K, int klen,
    float* __restrict__ Cf, ushort* __restrict__ Cb, ushort* __restrict__ Cv,
    int mode, int ldc)
{
    __shared__ ushort As[128 * LDP];   // 18,432 B
    __shared__ ushort Bs[128 * LDP];   // 18,432 B (total 36,864 B)

    const int tid = threadIdx.x;
    const int wv  = tid >> 6;         // wave 0..3
    const int ln  = tid & 63;
    const int row0 = blockIdx.y * 128;
    const int col0 = blockIdx.x * 128;
    const int kbase = blockIdx.z * klen;
    const int wr = (wv >> 1) * 64;
    const int wc = (wv & 1) * 64;
    const int l15 = ln & 15;
    const int lq  = ln >> 4;          // 0..3

    f32x4 acc[4][4];
    #pragma unroll
    for (int i = 0; i < 4; i++)
        #pragma unroll
        for (int j = 0; j < 4; j++)
            acc[i][j] = (f32x4){0.f, 0.f, 0.f, 0.f};

    // staging map: thread covers rows srow + 32*i (i=0..3), 16 B at scol.
    // each wave-instr: 8 rows x 8 lanes x 16B = contiguous 128 B per row (coalesced).
    const int srow = tid >> 3;          // 0..31
    const int scol = (tid & 7) * 8;     // ushort col offset (0,8,..,56)
    const ushort* gA = A  + (size_t)(row0 + srow) * K + kbase + scol;
    const ushort* gB = Bt + (size_t)(col0 + srow) * K + kbase + scol;
    const int ldsoff = srow * LDP + scol;

    uint4 ra[4], rb[4];
    #pragma unroll
    for (int i = 0; i < 4; i++) {
        ra[i] = *(const uint4*)(gA + (size_t)i * 32 * K);
        rb[i] = *(const uint4*)(gB + (size_t)i * 32 * K);
    }

    const int iters = klen >> 6;   // BK = 64
    for (int it = 0; it < iters; ++it) {
        __syncthreads();   // all waves done ds_reading previous tile
        #pragma unroll
        for (int i = 0; i < 4; i++) {
            *(uint4*)&As[ldsoff + i * 32 * LDP] = ra[i];
            *(uint4*)&Bs[ldsoff + i * 32 * LDP] = rb[i];
        }
        __syncthreads();   // tile visible to all waves

        if (it + 1 < iters) {
            const int ko = (it + 1) * 64;
            #pragma unroll
            for (int i = 0; i < 4; i++) {
                ra[i] = *(const uint4*)(gA + (size_t)i * 32 * K + ko);
                rb[i] = *(const uint4*)(gB + (size_t)i * 32 * K + ko);
            }
        }

        #pragma unroll
        for (int s = 0; s < 2; s++) {
            bf16x8 af[4], bfr[4];
            #pragma unroll
            for (int mi = 0; mi < 4; mi++)
                af[mi] = *(const bf16x8*)&As[(wr + mi * 16 + l15) * LDP + s * 32 + lq * 8];
            #pragma unroll
            for (int ni = 0; ni < 4; ni++)
                bfr[ni] = *(const bf16x8*)&Bs[(wc + ni * 16 + l15) * LDP + s * 32 + lq * 8];
            #pragma unroll
            for (int mi = 0; mi < 4; mi++)
                #pragma unroll
                for (int ni = 0; ni < 4; ni++)
                    acc[mi][ni] = __builtin_amdgcn_mfma_f32_16x16x32_bf16(
                        af[mi], bfr[ni], acc[mi][ni], 0, 0, 0);
        }
    }

    // Epilogue. D layout: col = lane&15, row = (lane>>4)*4 + reg.
    #pragma unroll
    for (int mi = 0; mi < 4; mi++) {
        #pragma unroll
        for (int ni = 0; ni < 4; ni++) {
            #pragma unroll
            for (int r = 0; r < 4; r++) {
                int row = row0 + wr + mi * 16 + lq * 4 + r;
                int col = col0 + wc + ni * 16 + l15;
                float v = acc[mi][ni][r];
                if (mode == 0) {
                    Cf[(size_t)row * ldc + col] = v;
                } else if (mode == 2) {
                    if (col < DD) Cb[(size_t)row * DD + col] = f2bf(fmaxf(v, 0.0f));
                    else          Cv[(size_t)row * DD + (col - DD)] = f2bf(v);
                } else {
                    Cf[((size_t)blockIdx.z * BT + row) * ldc + col] = v;
                }
            }
        }
    }
}

// ------------- Tiled window kernel: block = (b, t-tile of 64, head) -------------
__global__ __launch_bounds__(256) void attn_window_kernel(
    const ushort* __restrict__ v,
    const float* __restrict__ Lp,
    const float* __restrict__ scale_w,
    ushort* __restrict__ x)
{
    const int blk = blockIdx.x;       // 256 blocks
    const int h  = blk & 3;
    const int tt = (blk >> 2) & 15;
    const int b  = blk >> 6;
    const int t0 = tt * TB;
    const int tid = threadIdx.x;
    const size_t PS = (size_t)BT * NL; // partial stride

    __shared__ ushort vs[HB][256];    // 53,248 B
    __shared__ float  cw[TB][42];

    const ushort* vb = v + (size_t)b * TT * DD + h * 256;
    #pragma unroll
    for (int i = 0; i < 13; i++) {
        int c = i * 256 + tid;
        int r = c >> 5;
        int cir = c & 31;
        int t = t0 - HALO + r;
        uint4 val = make_uint4(0, 0, 0, 0);
        if (t >= 0 && t < TT)
            val = *(const uint4*)(vb + (size_t)t * DD + cir * 8);
        *(uint4*)(&vs[r][cir * 8]) = val;
    }

    if (tid < TB) {
        const int bt = b * TT + t0 + tid;
        const float* Lb = Lp + (size_t)bt * NL;

        float s0 = scale_w[0], s1 = scale_w[1];
        float mm = fmaxf(s0, s1);
        float e0 = __expf(s0 - mm), e1 = __expf(s1 - mm);
        float inv01 = 1.0f / (e0 + e1);
        float sw0 = e0 * inv01, sw1 = e1 * inv01;

        float w0[C0], w1[C1];
        {
            const int off = h * C0;
            float m = -1e30f;
            #pragma unroll
            for (int j = 0; j < C0; j++) {
                w0[j] = Lb[off + j] + Lb[PS + off + j];
                m = fmaxf(m, w0[j]);
            }
            float s = 0.0f;
            #pragma unroll
            for (int j = 0; j < C0; j++) { w0[j] = __expf(w0[j] - m); s += w0[j]; }
            float inv = sw0 / s;
            #pragma unroll
            for (int j = 0; j < C0; j++) w0[j] *= inv;
        }
        {
            const int off = N0 + h * C1;
            float m = -1e30f;
            #pragma unroll
            for (int j = 0; j < C1; j++) {
                w1[j] = Lb[off + j] + Lb[PS + off + j];
                m = fmaxf(m, w1[j]);
            }
            float s = 0.0f;
            #pragma unroll
            for (int j = 0; j < C1; j++) { w1[j] = __expf(w1[j] - m); s += w1[j]; }
            float inv = sw1 / s;
            #pragma unroll
            for (int j = 0; j < C1; j++) w1[j] *= inv;
        }
        #pragma unroll
        for (int o = 0; o < C1; o++) {
            float w = w1[o];
            if (o >= 10 && o <= 30) w += w0[o - 10];
            cw[tid][o] = w;
        }
    }
    __syncthreads();

    const int tq = tid >> 6;
    const int dg = tid & 63;
    const int d  = dg * 4;

    for (int tloc = 0; tloc < 16; tloc++) {
        const int tp = tq * 16 + tloc;
        f32x4 acc = {0.f, 0.f, 0.f, 0.f};
        #pragma unroll
        for (int o = 0; o < C1; o++) {
            float w = cw[tp][o];
            ushort4 vv = *(const ushort4*)(&vs[tp + o][d]);
            acc[0] = fmaf(w, bf2f(vv.x), acc[0]);
            acc[1] = fmaf(w, bf2f(vv.y), acc[1]);
            acc[2] = fmaf(w, bf2f(vv.z), acc[2]);
            acc[3] = fmaf(w, bf2f(vv.w), acc[3]);
        }
        const int bt = b * TT + t0 + tp;
        ushort4 o4;
        o4.x = f2bf(acc[0]); o4.y = f2bf(acc[1]);
        o4.z = f2bf(acc[2]); o4.w = f2bf(acc[3]);
        *(ushort4*)(x + (size_t)bt * DD + h * 256 + d) = o4;
    }
}

// ---------------------------------- launch ----------------------------------
extern "C" void kernel_launch(void* const* d_in, const int* in_sizes, int n_in,
                              void* d_out, int out_size, void* d_ws, size_t ws_size,
                              hipStream_t stream)
{
    const float* query   = (const float*)d_in[0];
    const float* W_qv    = (const float*)d_in[3];
    const float* W2_0    = (const float*)d_in[4];
    const float* W2_1    = (const float*)d_in[5];
    const float* scale_w = (const float*)d_in[6];
    const float* W_out   = (const float*)d_in[7];
    float* out = (float*)d_out;

    // Workspace layout. logitsP (8 MB) aliases query_bf (dead after qv GEMM).
    char* ws = (char*)d_ws;
    ushort* W2T      = (ushort*)ws;                 ws += (size_t)NL * DD * 2;        // 0.5 MB
    ushort* WoutT    = (ushort*)ws;                 ws += (size_t)DD * DD * 2;        // 2 MB
    ushort* query_bf = (ushort*)ws;
    float*  logitsP  = (float*)ws;                  ws += (size_t)BT * DD * 2;        // 8 MB
    ushort* WqvT     = (ushort*)ws;                 ws += (size_t)2 * DD * DD * 2;    // 4 MB
    ushort* reluq    = (ushort*)ws;                 ws += (size_t)BT * DD * 2;        // 8 MB
    ushort* vbuf     = (ushort*)ws;                 ws += (size_t)BT * DD * 2;        // 8 MB
    ushort* xbuf     = (ushort*)ws;                 ws += (size_t)BT * DD * 2;        // 8 MB

    // 0) all conversions in one launch
    convert_all<<<R4, 256, 0, stream>>>(query, query_bf, W_qv, WqvT,
                                        W_out, WoutT, W2_0, W2_1, W2T);

    // 1) qv GEMM: [4096,1024]x[1024,2048] -> reluq bf16 + v bf16 (512 blocks, 16 iters)
    {   dim3 grid(2 * DD / 128, BT / 128, 1);
        gemm_pipe<<<grid, 256, 0, stream>>>(query_bf, WqvT, DD, DD,
                                            nullptr, reluq, vbuf, 2, 0); }
    // 2) logits GEMM split-K=2: relu(q) x W2T -> logitsP (128 blocks, 8 iters)
    {   dim3 grid(NL / 128, BT / 128, KSPLIT);
        gemm_pipe<<<grid, 256, 0, stream>>>(reluq, W2T, DD, DD / KSPLIT,
                                            logitsP, nullptr, nullptr, 3, NL); }
    // 3) softmax (+partial sum) + sliding window -> xbuf bf16
    attn_window_kernel<<<256, 256, 0, stream>>>(vbuf, logitsP, scale_w, xbuf);

    // 4) out GEMM: x x WoutT -> out f32 (256 blocks, 16 iters)
    {   dim3 grid(DD / 128, BT / 128, 1);
        gemm_pipe<<<grid, 256, 0, stream>>>(xbuf, WoutT, DD, DD,
                                            out, nullptr, nullptr, 0, DD); }
}

// Round 9
// 212.087 us; speedup vs baseline: 1.3764x; 1.3764x over previous
//
#include <hip/hip_runtime.h>
#include <hip/hip_bf16.h>
#include <math.h>

// Problem dims (fixed by reference)
#define BB 4
#define TT 1024
#define DD 1024
#define HPS 4          // heads per scale
#define C0 21
#define C1 41
#define N0 (HPS * C0)  // 84
#define N1 (HPS * C1)  // 164
#define NL 256         // padded combined logits width (84 + 164 = 248 -> 256)
#define BT (BB * TT)   // 4096
#define TB 64          // t-tile for window kernel
#define HALO 20
#define HB (TB + 2 * HALO)  // 104 rows staged
#define KSPLIT 2       // split-K for logits GEMM

typedef unsigned int uint;
typedef __bf16 bf16x8 __attribute__((ext_vector_type(8)));
typedef float f32x4 __attribute__((ext_vector_type(4)));

__device__ __forceinline__ ushort f2bf(float f) {
    union { float f; uint u; } v; v.f = f;
    uint u = v.u;
    uint r = (u + 0x7FFFu + ((u >> 16) & 1u)) >> 16;
    return (ushort)r;
}
__device__ __forceinline__ float bf2f(ushort s) {
    union { uint u; float f; } v; v.u = ((uint)s) << 16;
    return v.f;
}

// ---------------- fused conversion kernel ----------------
#define RQ  4096
#define R1  (RQ + 2048)
#define R2  (R1 + 1024)
#define R3  (R2 + 96)
#define R4  (R3 + 192)

__device__ __forceinline__ void transpose_tile(
    const float* __restrict__ in, ushort* __restrict__ out,
    int K, int Nin, int n_base, int Npad, int nx, int ky, int tid)
{
    __shared__ float tile[32][33];
    const int tx = tid & 31;
    const int ty = tid >> 5;   // 0..7
    const int n0 = nx * 32;
    const int k0 = ky * 32;
    #pragma unroll
    for (int i = 0; i < 4; i++) {
        int k = k0 + ty + i * 8;
        int n = n0 + tx;
        float v = (k < K && n < Nin) ? in[(size_t)k * Nin + n] : 0.0f;
        tile[ty + i * 8][tx] = v;
    }
    __syncthreads();
    #pragma unroll
    for (int i = 0; i < 4; i++) {
        int n = n0 + ty + i * 8;
        int k = k0 + tx;
        if (n < Npad && k < K)
            out[(size_t)(n_base + n) * K + k] = f2bf(tile[tx][ty + i * 8]);
    }
}

__global__ __launch_bounds__(256) void convert_all(
    const float* __restrict__ query, ushort* __restrict__ query_bf,
    const float* __restrict__ W_qv,  ushort* __restrict__ WqvT,
    const float* __restrict__ W_out, ushort* __restrict__ WoutT,
    const float* __restrict__ W2_0, const float* __restrict__ W2_1,
    ushort* __restrict__ W2T)
{
    const int blk = blockIdx.x;
    const int tid = threadIdx.x;
    if (blk < RQ) {
        int i = blk * 1024 + tid * 4;
        float4 v = *(const float4*)(query + i);
        ushort4 o;
        o.x = f2bf(v.x); o.y = f2bf(v.y); o.z = f2bf(v.z); o.w = f2bf(v.w);
        *(ushort4*)(query_bf + i) = o;
    } else if (blk < R1) {
        int idx = blk - RQ;                // 64 x 32
        transpose_tile(W_qv, WqvT, DD, 2 * DD, 0, 2 * DD, idx & 63, idx >> 6, tid);
    } else if (blk < R2) {
        int idx = blk - R1;                // 32 x 32
        transpose_tile(W_out, WoutT, DD, DD, 0, DD, idx & 31, idx >> 5, tid);
    } else if (blk < R3) {
        int idx = blk - R2;                // 3 x 32
        transpose_tile(W2_0, W2T, DD, N0, 0, N0, idx % 3, idx / 3, tid);
    } else {
        int idx = blk - R3;                // 6 x 32
        transpose_tile(W2_1, W2T, DD, N1, N0, NL - N0, idx % 6, idx / 6, tid);
    }
}

// ---- bf16 MFMA GEMM, 128x128 tile, BK=32, VGPR depth-2 prefetch + ds_write ----
// A: [M][K] bf16 row-major. Bt: [N][K] bf16 row-major.
// LDS: k-major [kblk 0..3][row 0..127][8] — zero-conflict reads (R3/R6-measured)
// AND zero-conflict writes (thread t -> row t&127, chunks 2(t>>7), 2(t>>7)+1:
// each ds_write_b128 wave-instr is 64 x 16 B sequential).
// Depth-2 register prefetch: loads for it+2 issued ~2 compute phases before use.
// K, klen multiples of 64 (iters even).
// MODE 0: Cf[row*ldc+col] = acc
// MODE 2: col<DD -> Cb = bf16(relu(acc)); else Cv = bf16(acc)
// MODE 3: Cf[(bz*BT + row)*ldc + col] = acc   (split-K partial)
template <int MODE>
__global__ __launch_bounds__(256) void gemm_pipe(
    const ushort* __restrict__ A, const ushort* __restrict__ Bt,
    int K, int klen,
    float* __restrict__ Cf, ushort* __restrict__ Cb, ushort* __restrict__ Cv,
    int ldc)
{
    __shared__ ushort As[4 * 128 * 8];   // 8 KB
    __shared__ ushort Bs[4 * 128 * 8];   // 8 KB

    const int tid = threadIdx.x;
    const int wv  = tid >> 6;         // wave 0..3
    const int ln  = tid & 63;
    const int row0 = blockIdx.y * 128;
    const int col0 = blockIdx.x * 128;
    const int kbase = blockIdx.z * klen;
    const int wr = (wv >> 1) * 64;
    const int wc = (wv & 1) * 64;
    const int l15 = ln & 15;
    const int lq  = ln >> 4;          // 0..3

    f32x4 acc[4][4];
    #pragma unroll
    for (int i = 0; i < 4; i++)
        #pragma unroll
        for (int j = 0; j < 4; j++)
            acc[i][j] = (f32x4){0.f, 0.f, 0.f, 0.f};

    // staging map: thread t -> row t&127, chunk pair cp = 2*(t>>7)
    const int srow = tid & 127;
    const int cp   = (tid >> 7) * 2;    // 0 or 2
    const ushort* gA = A  + (size_t)(row0 + srow) * K + kbase + cp * 8;
    const ushort* gB = Bt + (size_t)(col0 + srow) * K + kbase + cp * 8;
    const int wo0 = cp * 1024 + srow * 8;        // LDS ushort offset, chunk cp
    const int wo1 = wo0 + 1024;                  // chunk cp+1

    const int iters = klen >> 5;   // BK = 32, even

    // depth-2 prefetch registers (scalars, fully unrolled -> no spill)
    uint4 a0 = *(const uint4*)(gA);      uint4 a0b = *(const uint4*)(gA + 8);
    uint4 b0 = *(const uint4*)(gB);      uint4 b0b = *(const uint4*)(gB + 8);
    uint4 a1 = *(const uint4*)(gA + 32); uint4 a1b = *(const uint4*)(gA + 40);
    uint4 b1 = *(const uint4*)(gB + 32); uint4 b1b = *(const uint4*)(gB + 40);

    for (int it = 0; it < iters; it += 2) {
        // ---------- even tile ----------
        __syncthreads();                       // all waves done reading LDS
        *(uint4*)&As[wo0] = a0;  *(uint4*)&As[wo1] = a0b;
        *(uint4*)&Bs[wo0] = b0;  *(uint4*)&Bs[wo1] = b0b;
        __syncthreads();
        if (it + 2 < iters) {
            const int ko = (it + 2) * 32;
            a0  = *(const uint4*)(gA + ko);      a0b = *(const uint4*)(gA + ko + 8);
            b0  = *(const uint4*)(gB + ko);      b0b = *(const uint4*)(gB + ko + 8);
        }
        {
            bf16x8 af[4], bfr[4];
            #pragma unroll
            for (int mi = 0; mi < 4; mi++)
                af[mi] = *(const bf16x8*)&As[lq * 1024 + (wr + mi * 16 + l15) * 8];
            #pragma unroll
            for (int ni = 0; ni < 4; ni++)
                bfr[ni] = *(const bf16x8*)&Bs[lq * 1024 + (wc + ni * 16 + l15) * 8];
            #pragma unroll
            for (int mi = 0; mi < 4; mi++)
                #pragma unroll
                for (int ni = 0; ni < 4; ni++)
                    acc[mi][ni] = __builtin_amdgcn_mfma_f32_16x16x32_bf16(
                        af[mi], bfr[ni], acc[mi][ni], 0, 0, 0);
        }
        // ---------- odd tile ----------
        __syncthreads();
        *(uint4*)&As[wo0] = a1;  *(uint4*)&As[wo1] = a1b;
        *(uint4*)&Bs[wo0] = b1;  *(uint4*)&Bs[wo1] = b1b;
        __syncthreads();
        if (it + 3 < iters) {
            const int ko = (it + 3) * 32;
            a1  = *(const uint4*)(gA + ko);      a1b = *(const uint4*)(gA + ko + 8);
            b1  = *(const uint4*)(gB + ko);      b1b = *(const uint4*)(gB + ko + 8);
        }
        {
            bf16x8 af[4], bfr[4];
            #pragma unroll
            for (int mi = 0; mi < 4; mi++)
                af[mi] = *(const bf16x8*)&As[lq * 1024 + (wr + mi * 16 + l15) * 8];
            #pragma unroll
            for (int ni = 0; ni < 4; ni++)
                bfr[ni] = *(const bf16x8*)&Bs[lq * 1024 + (wc + ni * 16 + l15) * 8];
            #pragma unroll
            for (int mi = 0; mi < 4; mi++)
                #pragma unroll
                for (int ni = 0; ni < 4; ni++)
                    acc[mi][ni] = __builtin_amdgcn_mfma_f32_16x16x32_bf16(
                        af[mi], bfr[ni], acc[mi][ni], 0, 0, 0);
        }
    }

    // Epilogue. D layout: col = lane&15, row = (lane>>4)*4 + reg.
    #pragma unroll
    for (int mi = 0; mi < 4; mi++) {
        #pragma unroll
        for (int ni = 0; ni < 4; ni++) {
            #pragma unroll
            for (int r = 0; r < 4; r++) {
                int row = row0 + wr + mi * 16 + lq * 4 + r;
                int col = col0 + wc + ni * 16 + l15;
                float v = acc[mi][ni][r];
                if (MODE == 0) {
                    Cf[(size_t)row * ldc + col] = v;
                } else if (MODE == 2) {
                    if (col < DD) Cb[(size_t)row * DD + col] = f2bf(fmaxf(v, 0.0f));
                    else          Cv[(size_t)row * DD + (col - DD)] = f2bf(v);
                } else {
                    Cf[((size_t)blockIdx.z * BT + row) * ldc + col] = v;
                }
            }
        }
    }
}

// ------------- Tiled window kernel: block = (b, t-tile of 64, head) -------------
__global__ __launch_bounds__(256) void attn_window_kernel(
    const ushort* __restrict__ v,
    const float* __restrict__ Lp,
    const float* __restrict__ scale_w,
    ushort* __restrict__ x)
{
    const int blk = blockIdx.x;       // 256 blocks
    const int h  = blk & 3;
    const int tt = (blk >> 2) & 15;
    const int b  = blk >> 6;
    const int t0 = tt * TB;
    const int tid = threadIdx.x;
    const size_t PS = (size_t)BT * NL; // partial stride

    __shared__ ushort vs[HB][256];    // 53,248 B
    __shared__ float  cw[TB][42];

    const ushort* vb = v + (size_t)b * TT * DD + h * 256;
    #pragma unroll
    for (int i = 0; i < 13; i++) {
        int c = i * 256 + tid;
        int r = c >> 5;
        int cir = c & 31;
        int t = t0 - HALO + r;
        uint4 val = make_uint4(0, 0, 0, 0);
        if (t >= 0 && t < TT)
            val = *(const uint4*)(vb + (size_t)t * DD + cir * 8);
        *(uint4*)(&vs[r][cir * 8]) = val;
    }

    if (tid < TB) {
        const int bt = b * TT + t0 + tid;
        const float* Lb = Lp + (size_t)bt * NL;

        float s0 = scale_w[0], s1 = scale_w[1];
        float mm = fmaxf(s0, s1);
        float e0 = __expf(s0 - mm), e1 = __expf(s1 - mm);
        float inv01 = 1.0f / (e0 + e1);
        float sw0 = e0 * inv01, sw1 = e1 * inv01;

        float w0[C0], w1[C1];
        {
            const int off = h * C0;
            float m = -1e30f;
            #pragma unroll
            for (int j = 0; j < C0; j++) {
                w0[j] = Lb[off + j] + Lb[PS + off + j];
                m = fmaxf(m, w0[j]);
            }
            float s = 0.0f;
            #pragma unroll
            for (int j = 0; j < C0; j++) { w0[j] = __expf(w0[j] - m); s += w0[j]; }
            float inv = sw0 / s;
            #pragma unroll
            for (int j = 0; j < C0; j++) w0[j] *= inv;
        }
        {
            const int off = N0 + h * C1;
            float m = -1e30f;
            #pragma unroll
            for (int j = 0; j < C1; j++) {
                w1[j] = Lb[off + j] + Lb[PS + off + j];
                m = fmaxf(m, w1[j]);
            }
            float s = 0.0f;
            #pragma unroll
            for (int j = 0; j < C1; j++) { w1[j] = __expf(w1[j] - m); s += w1[j]; }
            float inv = sw1 / s;
            #pragma unroll
            for (int j = 0; j < C1; j++) w1[j] *= inv;
        }
        #pragma unroll
        for (int o = 0; o < C1; o++) {
            float w = w1[o];
            if (o >= 10 && o <= 30) w += w0[o - 10];
            cw[tid][o] = w;
        }
    }
    __syncthreads();

    const int tq = tid >> 6;
    const int dg = tid & 63;
    const int d  = dg * 4;

    for (int tloc = 0; tloc < 16; tloc++) {
        const int tp = tq * 16 + tloc;
        f32x4 acc = {0.f, 0.f, 0.f, 0.f};
        #pragma unroll
        for (int o = 0; o < C1; o++) {
            float w = cw[tp][o];
            ushort4 vv = *(const ushort4*)(&vs[tp + o][d]);
            acc[0] = fmaf(w, bf2f(vv.x), acc[0]);
            acc[1] = fmaf(w, bf2f(vv.y), acc[1]);
            acc[2] = fmaf(w, bf2f(vv.z), acc[2]);
            acc[3] = fmaf(w, bf2f(vv.w), acc[3]);
        }
        const int bt = b * TT + t0 + tp;
        ushort4 o4;
        o4.x = f2bf(acc[0]); o4.y = f2bf(acc[1]);
        o4.z = f2bf(acc[2]); o4.w = f2bf(acc[3]);
        *(ushort4*)(x + (size_t)bt * DD + h * 256 + d) = o4;
    }
}

// ---------------------------------- launch ----------------------------------
extern "C" void kernel_launch(void* const* d_in, const int* in_sizes, int n_in,
                              void* d_out, int out_size, void* d_ws, size_t ws_size,
                              hipStream_t stream)
{
    const float* query   = (const float*)d_in[0];
    const float* W_qv    = (const float*)d_in[3];
    const float* W2_0    = (const float*)d_in[4];
    const float* W2_1    = (const float*)d_in[5];
    const float* scale_w = (const float*)d_in[6];
    const float* W_out   = (const float*)d_in[7];
    float* out = (float*)d_out;

    // Workspace layout. logitsP (8 MB) aliases query_bf (dead after qv GEMM).
    char* ws = (char*)d_ws;
    ushort* W2T      = (ushort*)ws;                 ws += (size_t)NL * DD * 2;        // 0.5 MB
    ushort* WoutT    = (ushort*)ws;                 ws += (size_t)DD * DD * 2;        // 2 MB
    ushort* query_bf = (ushort*)ws;
    float*  logitsP  = (float*)ws;                  ws += (size_t)BT * DD * 2;        // 8 MB
    ushort* WqvT     = (ushort*)ws;                 ws += (size_t)2 * DD * DD * 2;    // 4 MB
    ushort* reluq    = (ushort*)ws;                 ws += (size_t)BT * DD * 2;        // 8 MB
    ushort* vbuf     = (ushort*)ws;                 ws += (size_t)BT * DD * 2;        // 8 MB
    ushort* xbuf     = (ushort*)ws;                 ws += (size_t)BT * DD * 2;        // 8 MB

    // 0) all conversions in one launch
    convert_all<<<R4, 256, 0, stream>>>(query, query_bf, W_qv, WqvT,
                                        W_out, WoutT, W2_0, W2_1, W2T);

    // 1) qv GEMM: [4096,1024]x[1024,2048] -> reluq bf16 + v bf16 (512 blocks, 32 iters)
    {   dim3 grid(2 * DD / 128, BT / 128, 1);
        gemm_pipe<2><<<grid, 256, 0, stream>>>(query_bf, WqvT, DD, DD,
                                               nullptr, reluq, vbuf, 0); }
    // 2) logits GEMM split-K=2: relu(q) x W2T -> logitsP (128 blocks, 16 iters)
    {   dim3 grid(NL / 128, BT / 128, KSPLIT);
        gemm_pipe<3><<<grid, 256, 0, stream>>>(reluq, W2T, DD, DD / KSPLIT,
                                               logitsP, nullptr, nullptr, NL); }
    // 3) softmax (+partial sum) + sliding window -> xbuf bf16
    attn_window_kernel<<<256, 256, 0, stream>>>(vbuf, logitsP, scale_w, xbuf);

    // 4) out GEMM: x x WoutT -> out f32 (256 blocks, 32 iters)
    {   dim3 grid(DD / 128, BT / 128, 1);
        gemm_pipe<0><<<grid, 256, 0, stream>>>(xbuf, WoutT, DD, DD,
                                               out, nullptr, nullptr, DD); }
}